// Round 1
// baseline (225.064 us; speedup 1.0000x reference)
//
#include <hip/hip_runtime.h>

typedef float  f32x4  __attribute__((ext_vector_type(4)));
typedef __bf16 bf16x8 __attribute__((ext_vector_type(8)));
typedef unsigned short u16x8 __attribute__((ext_vector_type(8)));

#define LOG2E 1.44269504088896f

__device__ __forceinline__ unsigned short f2bf(float f) {
    unsigned u = __builtin_bit_cast(unsigned, f);
    u = (u + 0x7fffu + ((u >> 16) & 1u)) >> 16;   // RNE
    return (unsigned short)u;
}
__device__ __forceinline__ float fsigm(float x) {
    return __builtin_amdgcn_rcpf(1.0f + __builtin_amdgcn_exp2f(-LOG2E * x));
}
__device__ __forceinline__ float ftanh(float x) {
    // tanh(x) = 1 - 2/(exp(2x)+1)
    return 1.0f - 2.0f * __builtin_amdgcn_rcpf(1.0f + __builtin_amdgcn_exp2f((2.0f * LOG2E) * x));
}

// WG: 256 threads = 4 waves, handles 16 batch elements for all 256 timesteps.
// Wave w computes gate-type w (cols [64w,64w+64) of B) via MFMA, then the
// elementwise update for hidden slice [16w,16w+16).
__global__ __launch_bounds__(256, 1) void lstm_fused(
    const float* __restrict__ x,      // [4096][256][16]
    const float* __restrict__ w_ih1,  // [256][16]
    const float* __restrict__ w_hh1,  // [256][64]
    const float* __restrict__ b_ih1, const float* __restrict__ b_hh1,
    const float* __restrict__ w_ih2,  // [4][64]
    const float* __restrict__ w_hh2,  // [4]
    const float* __restrict__ b_ih2, const float* __restrict__ b_hh2,
    const float* __restrict__ fc_w, const float* __restrict__ fc_b,
    float* __restrict__ out)          // [4096][256]
{
    // byte/word-XOR swizzles keep all b128 LDS ops at the 8-phase optimum
    __shared__ unsigned short A_h[16 * 64];    // h1 state bf16, [b][h], byte ^ ((b&7)<<4)
    __shared__ unsigned short Xc[16 * 16 * 32];// x chunk bf16, [b][tt][i] (i 16..31 zero), byte ^ ((b&7)<<4)
    __shared__ float Pre[256 * 16];            // preacts, [n][b], word ^ ((n&7)<<2)
    __shared__ float Pre2[16 * 4];             // layer-2 preacts [b][g]
    __shared__ float Ybuf[16 * 16];            // [b][tt]

    const int tid = threadIdx.x;
    const int wv  = tid >> 6;
    const int l   = tid & 63;
    const int col = l & 15;
    const int hi  = l >> 4;
    const int b0  = blockIdx.x * 16;

    for (int i = tid; i < 16 * 64; i += 256) A_h[i] = 0;

    // ---- B fragments in registers (loaded once) ----
    // B[k][n]: k 0..63 = W_hh1[n][k]; 64..79 = W_ih1[n][k-64]; 80..95 = 0.
    // Tile 4 (wave 3 only): n=256..259 -> W_ih2 rows (layer-2 input proj), x-rows zero.
    bf16x8 Bf[5][3];
    #pragma unroll
    for (int c = 0; c < 5; ++c) {
        if (c == 4 && wv != 3) continue;
        const int n = (c < 4 ? (wv * 64 + c * 16) : 256) + col;
        #pragma unroll
        for (int ks = 0; ks < 3; ++ks) {
            u16x8 tmp;
            #pragma unroll
            for (int j = 0; j < 8; ++j) {
                const int k = ks * 32 + hi * 8 + j;
                float v = 0.0f;
                if (c < 4) {
                    if (k < 64)      v = w_hh1[n * 64 + k];
                    else if (k < 80) v = w_ih1[n * 16 + (k - 64)];
                } else {
                    if (col < 4 && k < 64) v = w_ih2[col * 64 + k];
                }
                tmp[j] = f2bf(v);
            }
            Bf[c][ks] = __builtin_bit_cast(bf16x8, tmp);
        }
    }

    // elementwise constants: this lane handles hidden he, batches 4*hi..4*hi+3
    const int he = wv * 16 + col;
    const float bsum0 = b_ih1[0 * 64 + he] + b_hh1[0 * 64 + he];
    const float bsum1 = b_ih1[1 * 64 + he] + b_hh1[1 * 64 + he];
    const float bsum2 = b_ih1[2 * 64 + he] + b_hh1[2 * 64 + he];
    const float bsum3 = b_ih1[3 * 64 + he] + b_hh1[3 * 64 + he];

    // layer-2 constants
    const float b2s0 = b_ih2[0] + b_hh2[0], b2s1 = b_ih2[1] + b_hh2[1];
    const float b2s2 = b_ih2[2] + b_hh2[2], b2s3 = b_ih2[3] + b_hh2[3];
    const float wh0 = w_hh2[0], wh1 = w_hh2[1], wh2g = w_hh2[2], wh3 = w_hh2[3];
    const float fcw = fc_w[0], fcb = fc_b[0];

    // x chunk prefetch: thread (bx, part) owns x[b0+bx][t0+part][0..15]
    const int bx = tid >> 4;
    const int part = tid & 15;
    const float* xrow = x + ((size_t)(b0 + bx) * 256) * 16;
    f32x4 xq0, xq1, xq2, xq3;
    {
        const f32x4* p = (const f32x4*)(xrow + part * 16);
        xq0 = p[0]; xq1 = p[1]; xq2 = p[2]; xq3 = p[3];
    }

    f32x4 c1 = {0.f, 0.f, 0.f, 0.f};
    float h2 = 0.f, c2 = 0.f;

    __syncthreads();

    for (int t = 0; t < 256; ++t) {
        const int tt = t & 15;
        if (tt == 0) {
            // write prefetched x chunk (full 64B rows: 16 data + 16 zeros, keeps swizzle closed)
            u16x8 lo, hw, z = {0, 0, 0, 0, 0, 0, 0, 0};
            #pragma unroll
            for (int j = 0; j < 4; ++j) {
                lo[j] = f2bf(xq0[j]); lo[4 + j] = f2bf(xq1[j]);
                hw[j] = f2bf(xq2[j]); hw[4 + j] = f2bf(xq3[j]);
            }
            char* base = (char*)Xc;
            const int ba = bx * 1024 + part * 64;
            const int sw = (bx & 7) << 4;
            *(u16x8*)(base + ((ba + 0)  ^ sw)) = lo;
            *(u16x8*)(base + ((ba + 16) ^ sw)) = hw;
            *(u16x8*)(base + ((ba + 32) ^ sw)) = z;
            *(u16x8*)(base + ((ba + 48) ^ sw)) = z;
            if (t + 16 < 256) {   // prefetch next chunk; latency hidden by 16 iters
                const f32x4* p = (const f32x4*)(xrow + (t + 16 + part) * 16);
                xq0 = p[0]; xq1 = p[1]; xq2 = p[2]; xq3 = p[3];
            }
            __syncthreads();
        }

        // ---- A fragments: row b = col, k-chunk = hi*8 (contig 8 bf16) ----
        const int swa = (col & 7) << 4;
        bf16x8 a0 = __builtin_bit_cast(bf16x8, *(const u16x8*)((char*)A_h + ((col * 128 + 0  + hi * 16) ^ swa)));
        bf16x8 a1 = __builtin_bit_cast(bf16x8, *(const u16x8*)((char*)A_h + ((col * 128 + 64 + hi * 16) ^ swa)));
        bf16x8 a2 = __builtin_bit_cast(bf16x8, *(const u16x8*)((char*)Xc  + ((col * 1024 + tt * 64 + hi * 16) ^ swa)));

        // ---- MFMA: gate preacts for this wave's 64 columns ----
        #pragma unroll
        for (int c = 0; c < 4; ++c) {
            f32x4 acc = {0.f, 0.f, 0.f, 0.f};
            acc = __builtin_amdgcn_mfma_f32_16x16x32_bf16(a0, Bf[c][0], acc, 0, 0, 0);
            acc = __builtin_amdgcn_mfma_f32_16x16x32_bf16(a1, Bf[c][1], acc, 0, 0, 0);
            acc = __builtin_amdgcn_mfma_f32_16x16x32_bf16(a2, Bf[c][2], acc, 0, 0, 0);
            const int n = wv * 64 + c * 16 + col;
            *(f32x4*)&Pre[(n * 16 + hi * 4) ^ ((n & 7) << 2)] = acc;
        }
        if (wv == 3) {  // layer-2 input projection of h1_{t-1} (x-rows of B are zero)
            f32x4 acc = {0.f, 0.f, 0.f, 0.f};
            acc = __builtin_amdgcn_mfma_f32_16x16x32_bf16(a0, Bf[4][0], acc, 0, 0, 0);
            acc = __builtin_amdgcn_mfma_f32_16x16x32_bf16(a1, Bf[4][1], acc, 0, 0, 0);
            if (col < 4) {
                #pragma unroll
                for (int r = 0; r < 4; ++r) Pre2[(hi * 4 + r) * 4 + col] = acc[r];
            }
        }
        __syncthreads();

        // ---- elementwise layer 1: hidden he, batches 4*hi+r ----
        const int n0 = he, n1 = 64 + he, n2 = 128 + he, n3 = 192 + he;
        const f32x4 P0 = *(const f32x4*)&Pre[(n0 * 16 + hi * 4) ^ ((n0 & 7) << 2)];
        const f32x4 P1 = *(const f32x4*)&Pre[(n1 * 16 + hi * 4) ^ ((n1 & 7) << 2)];
        const f32x4 P2 = *(const f32x4*)&Pre[(n2 * 16 + hi * 4) ^ ((n2 & 7) << 2)];
        const f32x4 P3 = *(const f32x4*)&Pre[(n3 * 16 + hi * 4) ^ ((n3 & 7) << 2)];
        #pragma unroll
        for (int r = 0; r < 4; ++r) {
            const float iv = fsigm(P0[r] + bsum0);
            const float fv = fsigm(P1[r] + bsum1);
            const float gv = ftanh(P2[r] + bsum2);
            const float ov = fsigm(P3[r] + bsum3);
            const float cn = fv * c1[r] + iv * gv;
            c1[r] = cn;
            const float h1v = ov * ftanh(cn);
            const int bb = hi * 4 + r;
            *(unsigned short*)((char*)A_h + ((bb * 128 + he * 2) ^ ((bb & 7) << 4))) = f2bf(h1v);
        }

        // ---- layer 2 (one step behind) + FC, wave 3 lanes 0..15 (lane = batch) ----
        if (wv == 3 && l < 16 && t > 0) {
            const int s = t - 1;
            const f32x4 p2 = *(const f32x4*)&Pre2[l * 4];
            const float i2 = fsigm(p2[0] + wh0 * h2 + b2s0);
            const float f2 = fsigm(p2[1] + wh1 * h2 + b2s1);
            const float g2 = ftanh(p2[2] + wh2g * h2 + b2s2);
            const float o2 = fsigm(p2[3] + wh3 * h2 + b2s3);
            c2 = f2 * c2 + i2 * g2;
            h2 = o2 * ftanh(c2);
            Ybuf[l * 16 + (s & 15)] = fcw * h2 + fcb;
            if ((s & 15) == 15) {  // coalesced 64B flush per batch row
                float* op = out + (size_t)(b0 + l) * 256 + (s - 15);
                const f32x4* yb = (const f32x4*)&Ybuf[l * 16];
                ((f32x4*)op)[0] = yb[0]; ((f32x4*)op)[1] = yb[1];
                ((f32x4*)op)[2] = yb[2]; ((f32x4*)op)[3] = yb[3];
            }
        }
        __syncthreads();
    }

    // ---- epilogue: layer-2 step for s = 255 (uses h1_255 now in A_h) ----
    if (wv == 3) {
        const int swa = (col & 7) << 4;
        bf16x8 a0 = __builtin_bit_cast(bf16x8, *(const u16x8*)((char*)A_h + ((col * 128 + 0  + hi * 16) ^ swa)));
        bf16x8 a1 = __builtin_bit_cast(bf16x8, *(const u16x8*)((char*)A_h + ((col * 128 + 64 + hi * 16) ^ swa)));
        f32x4 acc = {0.f, 0.f, 0.f, 0.f};
        acc = __builtin_amdgcn_mfma_f32_16x16x32_bf16(a0, Bf[4][0], acc, 0, 0, 0);
        acc = __builtin_amdgcn_mfma_f32_16x16x32_bf16(a1, Bf[4][1], acc, 0, 0, 0);
        if (col < 4) {
            #pragma unroll
            for (int r = 0; r < 4; ++r) Pre2[(hi * 4 + r) * 4 + col] = acc[r];
        }
        asm volatile("s_waitcnt lgkmcnt(0)" ::: "memory");
        if (l < 16) {
            const f32x4 p2 = *(const f32x4*)&Pre2[l * 4];
            const float i2 = fsigm(p2[0] + wh0 * h2 + b2s0);
            const float f2 = fsigm(p2[1] + wh1 * h2 + b2s1);
            const float g2 = ftanh(p2[2] + wh2g * h2 + b2s2);
            const float o2 = fsigm(p2[3] + wh3 * h2 + b2s3);
            c2 = f2 * c2 + i2 * g2;
            h2 = o2 * ftanh(c2);
            Ybuf[l * 16 + 15] = fcw * h2 + fcb;
            float* op = out + (size_t)(b0 + l) * 256 + 240;
            const f32x4* yb = (const f32x4*)&Ybuf[l * 16];
            ((f32x4*)op)[0] = yb[0]; ((f32x4*)op)[1] = yb[1];
            ((f32x4*)op)[2] = yb[2]; ((f32x4*)op)[3] = yb[3];
        }
    }
}

extern "C" void kernel_launch(void* const* d_in, const int* in_sizes, int n_in,
                              void* d_out, int out_size, void* d_ws, size_t ws_size,
                              hipStream_t stream) {
    const float* x     = (const float*)d_in[0];
    const float* w_ih1 = (const float*)d_in[1];
    const float* w_hh1 = (const float*)d_in[2];
    const float* b_ih1 = (const float*)d_in[3];
    const float* b_hh1 = (const float*)d_in[4];
    const float* w_ih2 = (const float*)d_in[5];
    const float* w_hh2 = (const float*)d_in[6];
    const float* b_ih2 = (const float*)d_in[7];
    const float* b_hh2 = (const float*)d_in[8];
    const float* fc_w  = (const float*)d_in[9];
    const float* fc_b  = (const float*)d_in[10];
    lstm_fused<<<dim3(256), dim3(256), 0, stream>>>(
        x, w_ih1, w_hh1, b_ih1, b_hh1, w_ih2, w_hh2, b_ih2, b_hh2, fc_w, fc_b,
        (float*)d_out);
}